// Round 9
// baseline (358.755 us; speedup 1.0000x reference)
//
#include <hip/hip_runtime.h>

#define HW 2304          // n = 48*48
#define CH 64            // DIM
#define NBLK 768         // persistent grid: 3 blocks/CU x 256 CU, co-residency guaranteed
typedef unsigned short ushort_t;
typedef __attribute__((ext_vector_type(8))) short bf16x8;
typedef __attribute__((ext_vector_type(4))) float f32x4;

#define QSCL (0.25f * 1.44269504088896340736f)   // attn scale * log2(e), folded into Qbf
#define SECM_SCL (0.25f / 144.f)
#define MFMA(a, b, c) __builtin_amdgcn_mfma_f32_16x16x32_bf16((a), (b), (c), 0, 0, 0)

static __device__ __forceinline__ ushort_t f2bf(float f) {
    union { float f; unsigned u; } v; v.f = f;
    unsigned r = v.u + 0x7FFFu + ((v.u >> 16) & 1u);   // RNE
    return (ushort_t)(r >> 16);
}
static __device__ __forceinline__ unsigned cvtpk(float a, float b) {  // lo=a, hi=b
    unsigned r;
    asm("v_cvt_pk_bf16_f32 %0, %1, %2" : "=v"(r) : "v"(a), "v"(b));
    return r;
}
union U8 { unsigned u[4]; bf16x8 v; };

// ---------------------------------------------------------------------------
// K_init: zero grid-barrier state + sacc (d_ws is re-poisoned 0xAA每 replay).
// ---------------------------------------------------------------------------
__global__ __launch_bounds__(256) void k_init(int* __restrict__ bar, float* __restrict__ sacc)
{
    const int tid = threadIdx.x;
    if (tid < 16) bar[tid] = 0;
    #pragma unroll
    for (int i = 0; i < 8; ++i) sacc[i * 256 + tid] = 0.f;
}

// Grid barrier: sense-reversal, monotonic phase, agent-scope acquire/release
// (same fence mechanism as cooperative grid.sync -> cross-XCD L2 safe).
static __device__ __forceinline__ void gridbar(int* bar, int phase)
{
    __syncthreads();
    if (threadIdx.x == 0) {
        int prev = __hip_atomic_fetch_add(&bar[0], 1, __ATOMIC_ACQ_REL, __HIP_MEMORY_SCOPE_AGENT);
        if (prev == NBLK - 1) {
            __hip_atomic_store(&bar[0], 0, __ATOMIC_RELAXED, __HIP_MEMORY_SCOPE_AGENT);
            __hip_atomic_store(&bar[1], phase, __ATOMIC_RELEASE, __HIP_MEMORY_SCOPE_AGENT);
        } else {
            while (__hip_atomic_load(&bar[1], __ATOMIC_ACQUIRE, __HIP_MEMORY_SCOPE_AGENT) < phase)
                __builtin_amdgcn_s_sleep(1);
        }
    }
    __syncthreads();
}

// ---------------------------------------------------------------------------
// K_mega: P0 wconv | P1 ln+proj | P2 attn | P3 tail, grid barriers between.
// All phase bodies are the round-8-verified kernels, re-indexed only.
// ---------------------------------------------------------------------------
__global__ __launch_bounds__(256, 3) void k_mega(
    const float* __restrict__ x, const float* __restrict__ y,
    const float* __restrict__ ln1g, const float* __restrict__ ln1b,
    const float* __restrict__ wsa1, const float* __restrict__ wsa2,
    const float* __restrict__ wse1, const float* __restrict__ wse2,
    const float* __restrict__ w_out, const float* __restrict__ b_out,
    const float* __restrict__ ln2g, const float* __restrict__ ln2b,
    const float* __restrict__ w1, const float* __restrict__ mb1,
    const float* __restrict__ w2, const float* __restrict__ mb2,
    float* __restrict__ y1f, float* __restrict__ sacc, int* __restrict__ bar,
    ushort_t* __restrict__ qbf, ushort_t* __restrict__ kbf,
    ushort_t* __restrict__ vtbf, ushort_t* __restrict__ obf,
    ushort_t* __restrict__ wsa1T, ushort_t* __restrict__ wsa2T,
    ushort_t* __restrict__ wse1T, ushort_t* __restrict__ wse2T,
    ushort_t* __restrict__ w_outT, ushort_t* __restrict__ wT1, ushort_t* __restrict__ wT2,
    float* __restrict__ out)
{
    union SM {
        struct { uint4 pbuf4[4][80]; f32x4 cacc[4][64]; float clsum[4][64];
                 float sraw[256]; float smv[256]; } a;                     // 12288 B
        struct { float xtile[16][68]; ushort_t hh[16 * 264 + 16]; } t;     // 12832 B
        struct { ushort_t A[4][416]; ushort_t B[4][416]; } l;              //  6656 B
    };
    __shared__ SM sm;
    const f32x4 zero4 = {0.f, 0.f, 0.f, 0.f};

    // ================= P0: weight conversion (grid-stride, single pass) ====
    {
        const int idx = blockIdx.x * 256 + threadIdx.x;
        if (idx < 20480) {                    // five 64x64 transposes
            const int mi = idx >> 12, o = idx & 4095;
            const float* s = mi == 0 ? wsa1 : mi == 1 ? wsa2 : mi == 2 ? wse1 : mi == 3 ? wse2 : w_out;
            ushort_t* d = mi == 0 ? wsa1T : mi == 1 ? wsa2T : mi == 2 ? wse1T : mi == 3 ? wse2T : w_outT;
            d[o] = f2bf(s[(o & 63) * 64 + (o >> 6)]);
        } else if (idx < 36864) {             // wT1[j][c] = w1[c][j]
            const int o = idx - 20480;
            wT1[o] = f2bf(w1[(o & 63) * 256 + (o >> 6)]);
        } else if (idx < 53248) {             // wT2[j][c] = w2[c][j]
            const int o = idx - 36864;
            wT2[o] = f2bf(w2[(o & 255) * 64 + (o >> 8)]);
        }
    }
    gridbar(bar, 1);

    // ================= P1: LN + dual projection (2304 wave-tasks) ==========
    {
        const int tid = threadIdx.x;
        const int w = tid >> 6, lane = tid & 63;
        const int task = blockIdx.x + w * NBLK;
        if (task < 2304) {
            const int jt = task / 576;
            const int t576 = task % 576;
            const int rt = t576 % 144;
            const int b  = (t576 / 144) & 1;
            const int branch = t576 / 288;
            const int r = lane & 15, cg = lane >> 4;
            const int q0 = rt * 16;
            const float* xin = (branch ? y : x) + (size_t)b * CH * HW + q0 + r;
            float lo[8], hi[8];
            float s = 0.f, sq = 0.f;
            #pragma unroll
            for (int ki = 0; ki < 8; ++ki) {
                lo[ki] = xin[(size_t)(8 * cg + ki) * HW];
                hi[ki] = xin[(size_t)(32 + 8 * cg + ki) * HW];
                s += lo[ki] + hi[ki];
                sq += lo[ki] * lo[ki] + hi[ki] * hi[ki];
            }
            s  += __shfl_xor(s, 16);  s  += __shfl_xor(s, 32);
            sq += __shfl_xor(sq, 16); sq += __shfl_xor(sq, 32);
            const float m  = s * (1.f / 64.f);
            const float rs = rsqrtf(sq * (1.f / 64.f) - m * m + 1e-5f);
            float ga[16], be[16];
            {
                const float4* gp = (const float4*)ln1g;
                const float4* bp = (const float4*)ln1b;
                *(float4*)&ga[0]  = gp[2 * cg];     *(float4*)&ga[4]  = gp[2 * cg + 1];
                *(float4*)&ga[8]  = gp[8 + 2 * cg]; *(float4*)&ga[12] = gp[9 + 2 * cg];
                *(float4*)&be[0]  = bp[2 * cg];     *(float4*)&be[4]  = bp[2 * cg + 1];
                *(float4*)&be[8]  = bp[8 + 2 * cg]; *(float4*)&be[12] = bp[9 + 2 * cg];
            }
            float nlo[8], nhi[8];
            #pragma unroll
            for (int ki = 0; ki < 8; ++ki) {
                nlo[ki] = (lo[ki] - m) * rs * ga[ki]     + be[ki];
                nhi[ki] = (hi[ki] - m) * rs * ga[8 + ki] + be[8 + ki];
            }
            U8 alo, ahi;
            #pragma unroll
            for (int p = 0; p < 4; ++p) {
                alo.u[p] = cvtpk(nlo[2 * p], nlo[2 * p + 1]);
                ahi.u[p] = cvtpk(nhi[2 * p], nhi[2 * p + 1]);
            }
            const ushort_t* wp1 = branch ? wsa1T : wse1T;
            const ushort_t* wp2 = branch ? wsa2T : wse2T;
            const int bh = b * 4 + jt;
            bf16x8 bl1 = *(const bf16x8*)(wp1 + (jt * 16 + r) * 64 + 8 * cg);
            bf16x8 bh1 = *(const bf16x8*)(wp1 + (jt * 16 + r) * 64 + 32 + 8 * cg);
            f32x4 acc1 = zero4;
            acc1 = MFMA(alo.v, bl1, acc1);
            acc1 = MFMA(ahi.v, bh1, acc1);
            bf16x8 bl2 = *(const bf16x8*)(wp2 + (jt * 16 + r) * 64 + 8 * cg);
            bf16x8 bh2 = *(const bf16x8*)(wp2 + (jt * 16 + r) * 64 + 32 + 8 * cg);
            f32x4 acc2 = zero4;
            acc2 = MFMA(alo.v, bl2, acc2);
            acc2 = MFMA(ahi.v, bh2, acc2);
            if (branch == 0) {
                uint2 pk1; pk1.x = cvtpk(acc1[0], acc1[1]); pk1.y = cvtpk(acc1[2], acc1[3]);
                *(uint2*)(vtbf + (size_t)(bh * 16 + r) * HW + q0 + 4 * cg) = pk1;
                *(uint2*)&sm.l.A[w][r * 24 + 4 * cg] = pk1;
                uint2 pk2; pk2.x = cvtpk(acc2[0], acc2[1]); pk2.y = cvtpk(acc2[2], acc2[3]);
                *(uint2*)&sm.l.B[w][r * 24 + 4 * cg] = pk2;
                bf16x8 af = {0, 0, 0, 0, 0, 0, 0, 0};
                bf16x8 bf_ = {0, 0, 0, 0, 0, 0, 0, 0};
                if (cg < 2) {
                    af  = *(const bf16x8*)&sm.l.A[w][r * 24 + 8 * cg];
                    bf_ = *(const bf16x8*)&sm.l.B[w][r * 24 + 8 * cg];
                }
                f32x4 sp = MFMA(af, bf_, zero4);
                #pragma unroll
                for (int ri = 0; ri < 4; ++ri)
                    atomicAdd(&sacc[bh * 256 + (4 * cg + ri) * 16 + r], sp[ri]);
            } else {
                #pragma unroll
                for (int ri = 0; ri < 4; ++ri) {
                    const int q = q0 + 4 * cg + ri;
                    y1f[((size_t)bh * HW + q) * 16 + r] = acc1[ri];
                    qbf[((size_t)bh * HW + q) * 16 + r] = f2bf(acc1[ri] * QSCL);
                    kbf[((size_t)bh * HW + q) * 16 + r] = f2bf(acc2[ri]);
                }
            }
        }
    }
    gridbar(bar, 2);

    // ================= P2: attention (1152 tasks, 4-wave k-split) ==========
    {
        const int tid = threadIdx.x;
        const int w = tid >> 6, lane = tid & 63;
        const int q16 = lane & 15, g = lane >> 4;
        unsigned char* pw = (unsigned char*)&sm.a.pbuf4[w][0];
        for (int t = blockIdx.x; t < 1152; t += NBLK) {
            const int qt = t % 144, bh = t / 144;
            const int q0 = qt * 16;
            sm.a.sraw[tid] = sacc[bh * 256 + tid] * SECM_SCL;
            __syncthreads();
            {
                const int i = tid >> 4;
                float mx = -1e30f;
                #pragma unroll
                for (int jj = 0; jj < 16; ++jj) mx = fmaxf(mx, sm.a.sraw[i * 16 + jj]);
                float sum = 0.f;
                #pragma unroll
                for (int jj = 0; jj < 16; ++jj) sum += __expf(sm.a.sraw[i * 16 + jj] - mx);
                sm.a.smv[tid] = __expf(sm.a.sraw[tid] - mx) / sum;
            }
            bf16x8 qfrag = {0, 0, 0, 0, 0, 0, 0, 0};
            if (g < 2) qfrag = *(const bf16x8*)(qbf + ((size_t)bh * HW + q0 + q16) * 16 + g * 8);
            const ushort_t* kbase = kbf + (size_t)bh * HW * 16;
            const ushort_t* vbase = vtbf + (size_t)(bh * 16 + q16) * HW;
            f32x4 oacc = zero4;
            float lsum = 0.f;
            #pragma unroll 2
            for (int wi = 0; wi < 18; ++wi) {
                const int k0 = w * 576 + wi * 32;
                bf16x8 kf0 = *(const bf16x8*)(kbase + (size_t)(k0 + q16) * 16 + (g & 1) * 8);
                bf16x8 kf1 = *(const bf16x8*)(kbase + (size_t)(k0 + 16 + q16) * 16 + (g & 1) * 8);
                f32x4 s0 = MFMA(kf0, qfrag, zero4);
                f32x4 s1 = MFMA(kf1, qfrag, zero4);
                const float e00 = exp2f(s0[0]), e01 = exp2f(s0[1]), e02 = exp2f(s0[2]), e03 = exp2f(s0[3]);
                const float e10 = exp2f(s1[0]), e11 = exp2f(s1[1]), e12 = exp2f(s1[2]), e13 = exp2f(s1[3]);
                lsum += ((e00 + e01) + (e02 + e03)) + ((e10 + e11) + (e12 + e13));
                *(unsigned*)(pw + q16 * 80 + 8 * g)      = cvtpk(e00, e01);
                *(unsigned*)(pw + q16 * 80 + 8 * g + 4)  = cvtpk(e02, e03);
                *(unsigned*)(pw + q16 * 80 + 32 + 8 * g) = cvtpk(e10, e11);
                *(unsigned*)(pw + q16 * 80 + 36 + 8 * g) = cvtpk(e12, e13);
                bf16x8 vfrag = *(const bf16x8*)(vbase + k0 + 8 * g);
                bf16x8 pfrag = *(const bf16x8*)(pw + q16 * 80 + 16 * g);
                oacc = MFMA(vfrag, pfrag, oacc);
            }
            sm.a.cacc[w][lane] = oacc;
            sm.a.clsum[w][lane] = lsum;
            __syncthreads();
            if (tid < 64) {
                f32x4 tt = sm.a.cacc[0][lane];
                float L = sm.a.clsum[0][lane];
                #pragma unroll
                for (int ww = 1; ww < 4; ++ww) {
                    f32x4 tw = sm.a.cacc[ww][lane];
                    tt[0] += tw[0]; tt[1] += tw[1]; tt[2] += tw[2]; tt[3] += tw[3];
                    L += sm.a.clsum[ww][lane];
                }
                L += __shfl_xor(L, 16);
                L += __shfl_xor(L, 32);
                const float invl = 1.f / L;
                const float* yrow = y1f + ((size_t)bh * HW + q0 + q16) * 16;
                float ya[16];
                #pragma unroll
                for (int i = 0; i < 4; ++i) *(float4*)&ya[4 * i] = ((const float4*)yrow)[i];
                float gate[4] = {0.f, 0.f, 0.f, 0.f};
                #pragma unroll
                for (int i = 0; i < 16; ++i) {
                    #pragma unroll
                    for (int rr = 0; rr < 4; ++rr) gate[rr] += ya[i] * sm.a.smv[i * 16 + g * 4 + rr];
                }
                const int b = bh >> 2, h = bh & 3;
                float r0 = tt[0] * invl * gate[0];
                float r1 = tt[1] * invl * gate[1];
                float r2 = tt[2] * invl * gate[2];
                float r3 = tt[3] * invl * gate[3];
                uint2 pk; pk.x = cvtpk(r0, r1); pk.y = cvtpk(r2, r3);
                *(uint2*)(obf + ((size_t)b * HW + q0 + q16) * 64 + h * 16 + g * 4) = pk;
            }
            __syncthreads();
        }
    }
    gridbar(bar, 3);

    // ================= P3: fused tail (288 block-tasks) ====================
    if (blockIdx.x < 288) {
        const int t = blockIdx.x;
        const int b = t / 144;
        const int q0 = (t % 144) * 16;
        const int tid = threadIdx.x;
        const int w = tid >> 6, lane = tid & 63;
        const int r = lane & 15, cg = lane >> 4;
        const ushort_t* arow = obf + ((size_t)b * HW + q0 + r) * 64;
        bf16x8 alo = *(const bf16x8*)(arow + 8 * cg);
        bf16x8 ahi = *(const bf16x8*)(arow + 32 + 8 * cg);
        {
            bf16x8 bl = *(const bf16x8*)(w_outT + (w * 16 + r) * 64 + 8 * cg);
            bf16x8 bh_ = *(const bf16x8*)(w_outT + (w * 16 + r) * 64 + 32 + 8 * cg);
            f32x4 acc = zero4;
            acc = MFMA(alo, bl, acc);
            acc = MFMA(ahi, bh_, acc);
            const int c = w * 16 + r;
            const float bo = b_out[c];
            float4 xr = *(const float4*)(x + (size_t)b * CH * HW + (size_t)c * HW + q0 + 4 * cg);
            sm.t.xtile[4 * cg + 0][c] = acc[0] + bo + xr.x;
            sm.t.xtile[4 * cg + 1][c] = acc[1] + bo + xr.y;
            sm.t.xtile[4 * cg + 2][c] = acc[2] + bo + xr.z;
            sm.t.xtile[4 * cg + 3][c] = acc[3] + bo + xr.w;
        }
        __syncthreads();
        float s = 0.f, sq = 0.f;
        #pragma unroll
        for (int j = 0; j < 16; ++j) {
            const float v = sm.t.xtile[r][cg * 16 + j];
            s += v; sq += v * v;
        }
        s  += __shfl_xor(s, 16);  s  += __shfl_xor(s, 32);
        sq += __shfl_xor(sq, 16); sq += __shfl_xor(sq, 32);
        const float m  = s * (1.f / 64.f);
        const float rs = rsqrtf(sq * (1.f / 64.f) - m * m + 1e-5f);
        float ga[16], be[16];
        {
            const float4* gp = (const float4*)ln2g;
            const float4* bp = (const float4*)ln2b;
            *(float4*)&ga[0]  = gp[2 * cg];     *(float4*)&ga[4]  = gp[2 * cg + 1];
            *(float4*)&ga[8]  = gp[8 + 2 * cg]; *(float4*)&ga[12] = gp[9 + 2 * cg];
            *(float4*)&be[0]  = bp[2 * cg];     *(float4*)&be[4]  = bp[2 * cg + 1];
            *(float4*)&be[8]  = bp[8 + 2 * cg]; *(float4*)&be[12] = bp[9 + 2 * cg];
        }
        float nlo[8], nhi[8];
        #pragma unroll
        for (int ki = 0; ki < 8; ++ki) {
            nlo[ki] = (sm.t.xtile[r][8 * cg + ki]      - m) * rs * ga[ki]     + be[ki];
            nhi[ki] = (sm.t.xtile[r][32 + 8 * cg + ki] - m) * rs * ga[8 + ki] + be[8 + ki];
        }
        U8 axlo, axhi;
        #pragma unroll
        for (int p = 0; p < 4; ++p) {
            axlo.u[p] = cvtpk(nlo[2 * p], nlo[2 * p + 1]);
            axhi.u[p] = cvtpk(nhi[2 * p], nhi[2 * p + 1]);
        }
        #pragma unroll
        for (int jj = 0; jj < 4; ++jj) {
            const int jt = 4 * w + jj;
            bf16x8 bl = *(const bf16x8*)(wT1 + (jt * 16 + r) * 64 + 8 * cg);
            bf16x8 bh_ = *(const bf16x8*)(wT1 + (jt * 16 + r) * 64 + 32 + 8 * cg);
            f32x4 acc = zero4;
            acc = MFMA(axlo.v, bl, acc);
            acc = MFMA(axhi.v, bh_, acc);
            const int c = jt * 16 + r;
            const float bias = mb1[c];
            #pragma unroll
            for (int ri = 0; ri < 4; ++ri) {
                float vv = acc[ri] + bias;
                vv = fmaxf(vv, 0.01f * vv);
                sm.t.hh[(4 * cg + ri) * 264 + c] = f2bf(vv);
            }
        }
        __syncthreads();
        bf16x8 ha[8];
        #pragma unroll
        for (int kw = 0; kw < 8; ++kw)
            ha[kw] = *(const bf16x8*)&sm.t.hh[r * 264 + kw * 32 + 8 * cg];
        f32x4 acc = zero4;
        #pragma unroll
        for (int kw = 0; kw < 8; ++kw) {
            bf16x8 bf_ = *(const bf16x8*)(wT2 + (w * 16 + r) * 256 + kw * 32 + 8 * cg);
            acc = MFMA(ha[kw], bf_, acc);
        }
        const int c = w * 16 + r;
        const float bias = mb2[c];
        float4 res;
        res.x = acc[0] + bias + sm.t.xtile[4 * cg + 0][c];
        res.y = acc[1] + bias + sm.t.xtile[4 * cg + 1][c];
        res.z = acc[2] + bias + sm.t.xtile[4 * cg + 2][c];
        res.w = acc[3] + bias + sm.t.xtile[4 * cg + 3][c];
        *(float4*)(out + (size_t)b * CH * HW + (size_t)c * HW + q0 + 4 * cg) = res;
    }
}

extern "C" void kernel_launch(void* const* d_in, const int* in_sizes, int n_in,
                              void* d_out, int out_size, void* d_ws, size_t ws_size,
                              hipStream_t stream)
{
    (void)in_sizes; (void)n_in; (void)out_size; (void)ws_size;
    const float* x     = (const float*)d_in[0];
    const float* y     = (const float*)d_in[1];
    const float* ln1_g = (const float*)d_in[2];
    const float* ln1_b = (const float*)d_in[3];
    const float* w_sa1 = (const float*)d_in[4];
    const float* w_sa2 = (const float*)d_in[5];
    const float* w_se1 = (const float*)d_in[6];
    const float* w_se2 = (const float*)d_in[7];
    const float* w_out = (const float*)d_in[8];
    const float* b_out = (const float*)d_in[9];
    const float* ln2_g = (const float*)d_in[10];
    const float* ln2_b = (const float*)d_in[11];
    const float* w1    = (const float*)d_in[12];
    const float* b1    = (const float*)d_in[13];
    const float* w2    = (const float*)d_in[14];
    const float* b2    = (const float*)d_in[15];
    float* out = (float*)d_out;

    const size_t NP = 8ull * HW * 16;              // 294912
    float* p = (float*)d_ws;
    float* y1f  = p;  p += NP;
    float* sacc = p;  p += 2048;
    int*   bar  = (int*)p;  p += 16;
    ushort_t* u = (ushort_t*)p;
    ushort_t* qbf   = u;  u += NP;
    ushort_t* kbf   = u;  u += NP;
    ushort_t* vtbf  = u;  u += NP;
    ushort_t* obf   = u;  u += NP;
    ushort_t* wsa1T = u;  u += 4096;
    ushort_t* wsa2T = u;  u += 4096;
    ushort_t* wse1T = u;  u += 4096;
    ushort_t* wse2T = u;  u += 4096;
    ushort_t* w_outT= u;  u += 4096;
    ushort_t* wT1   = u;  u += 16384;
    ushort_t* wT2   = u;  u += 16384;
    // total ~3.6 MB of d_ws

    k_init<<<1, 256, 0, stream>>>(bar, sacc);
    k_mega<<<NBLK, 256, 0, stream>>>(x, y, ln1_g, ln1_b,
                                     w_sa1, w_sa2, w_se1, w_se2,
                                     w_out, b_out, ln2_g, ln2_b,
                                     w1, b1, w2, b2,
                                     y1f, sacc, bar,
                                     qbf, kbf, vtbf, obf,
                                     wsa1T, wsa2T, wse1T, wse2T,
                                     w_outT, wT1, wT2,
                                     out);
}

// Round 10
// 124.782 us; speedup vs baseline: 2.8751x; 2.8751x over previous
//
#include <hip/hip_runtime.h>

#define HW 2304          // n = 48*48
#define CH 64            // DIM
typedef unsigned short ushort_t;
typedef __attribute__((ext_vector_type(8))) short bf16x8;
typedef __attribute__((ext_vector_type(4))) float f32x4;

#define QSCL (0.25f * 1.44269504088896340736f)   // attn scale * log2(e), folded into Qbf
#define INV_QSCL (1.0f / QSCL)
#define SECM_SCL (0.25f / 144.f)
#define MFMA(a, b, c) __builtin_amdgcn_mfma_f32_16x16x32_bf16((a), (b), (c), 0, 0, 0)

static __device__ __forceinline__ ushort_t f2bf(float f) {
    union { float f; unsigned u; } v; v.f = f;
    unsigned r = v.u + 0x7FFFu + ((v.u >> 16) & 1u);   // RNE
    return (ushort_t)(r >> 16);
}
static __device__ __forceinline__ float bf2f(ushort_t b) {
    union { unsigned u; float f; } v; v.u = ((unsigned)b) << 16;
    return v.f;
}
static __device__ __forceinline__ unsigned cvtpk(float a, float b) {  // lo=a, hi=b
    unsigned r;
    asm("v_cvt_pk_bf16_f32 %0, %1, %2" : "=v"(r) : "v"(a), "v"(b));
    return r;
}
union U8 { unsigned u[4]; bf16x8 v; };

// ---------------------------------------------------------------------------
// K1: LN + dual projection via MFMA, weights converted inline per-lane
// (no k_wconv pre-pass). grid (576, 4) x 64: 1 wave / 16 rows / 1 head.
// branch0 (x): x1 -> vtbf [bh][16][HW], x2 -> x2t [bh][16][HW]
// branch1 (y): y1*QSCL -> qbf [bh][n][16], y2 -> kbf [bh][n][16]
// ---------------------------------------------------------------------------
__global__ __launch_bounds__(64) void k_ln_proj(
    const float* __restrict__ x, const float* __restrict__ y,
    const float* __restrict__ g, const float* __restrict__ bb,
    const float* __restrict__ wsa1, const float* __restrict__ wsa2,
    const float* __restrict__ wse1, const float* __restrict__ wse2,
    ushort_t* __restrict__ qbf, ushort_t* __restrict__ kbf,
    ushort_t* __restrict__ vtbf, ushort_t* __restrict__ x2t)
{
    const int task = blockIdx.x;
    const int jt = blockIdx.y;
    const int rt = task % 144;
    const int b  = (task / 144) & 1;
    const int branch = task / 288;
    const int lane = threadIdx.x;
    const int r = lane & 15, cg = lane >> 4;
    const int q0 = rt * 16;
    // inline weight conversion: lane's B-frags = w^T row (jt*16+r), in-slices
    const float* wp1 = branch ? wsa1 : wse1;   // [in][out] f32
    const float* wp2 = branch ? wsa2 : wse2;
    const int oc = jt * 16 + r;
    U8 bl1, bh1, bl2, bh2;
    #pragma unroll
    for (int p = 0; p < 4; ++p) {
        bl1.u[p] = cvtpk(wp1[(8 * cg + 2 * p) * 64 + oc],      wp1[(8 * cg + 2 * p + 1) * 64 + oc]);
        bh1.u[p] = cvtpk(wp1[(32 + 8 * cg + 2 * p) * 64 + oc], wp1[(32 + 8 * cg + 2 * p + 1) * 64 + oc]);
        bl2.u[p] = cvtpk(wp2[(8 * cg + 2 * p) * 64 + oc],      wp2[(8 * cg + 2 * p + 1) * 64 + oc]);
        bh2.u[p] = cvtpk(wp2[(32 + 8 * cg + 2 * p) * 64 + oc], wp2[(32 + 8 * cg + 2 * p + 1) * 64 + oc]);
    }
    const float* in = (branch ? y : x) + (size_t)b * CH * HW + q0 + r;
    float lo[8], hi[8];
    float s = 0.f, sq = 0.f;
    #pragma unroll
    for (int ki = 0; ki < 8; ++ki) {
        lo[ki] = in[(size_t)(8 * cg + ki) * HW];
        hi[ki] = in[(size_t)(32 + 8 * cg + ki) * HW];
        s += lo[ki] + hi[ki];
        sq += lo[ki] * lo[ki] + hi[ki] * hi[ki];
    }
    s  += __shfl_xor(s, 16);  s  += __shfl_xor(s, 32);
    sq += __shfl_xor(sq, 16); sq += __shfl_xor(sq, 32);
    const float m  = s * (1.f / 64.f);
    const float rs = rsqrtf(sq * (1.f / 64.f) - m * m + 1e-5f);
    float ga[16], be[16];
    {
        const float4* gp = (const float4*)g;
        const float4* bp = (const float4*)bb;
        *(float4*)&ga[0]  = gp[2 * cg];     *(float4*)&ga[4]  = gp[2 * cg + 1];
        *(float4*)&ga[8]  = gp[8 + 2 * cg]; *(float4*)&ga[12] = gp[9 + 2 * cg];
        *(float4*)&be[0]  = bp[2 * cg];     *(float4*)&be[4]  = bp[2 * cg + 1];
        *(float4*)&be[8]  = bp[8 + 2 * cg]; *(float4*)&be[12] = bp[9 + 2 * cg];
    }
    float nlo[8], nhi[8];
    #pragma unroll
    for (int ki = 0; ki < 8; ++ki) {
        nlo[ki] = (lo[ki] - m) * rs * ga[ki]     + be[ki];
        nhi[ki] = (hi[ki] - m) * rs * ga[8 + ki] + be[8 + ki];
    }
    U8 alo, ahi;
    #pragma unroll
    for (int p = 0; p < 4; ++p) {
        alo.u[p] = cvtpk(nlo[2 * p], nlo[2 * p + 1]);
        ahi.u[p] = cvtpk(nhi[2 * p], nhi[2 * p + 1]);
    }
    const f32x4 zero4 = {0.f, 0.f, 0.f, 0.f};
    const int bh = b * 4 + jt;
    f32x4 acc1 = zero4;
    acc1 = MFMA(alo.v, bl1.v, acc1);
    acc1 = MFMA(ahi.v, bh1.v, acc1);
    f32x4 acc2 = zero4;
    acc2 = MFMA(alo.v, bl2.v, acc2);
    acc2 = MFMA(ahi.v, bh2.v, acc2);
    if (branch == 0) {
        uint2 pk1; pk1.x = cvtpk(acc1[0], acc1[1]); pk1.y = cvtpk(acc1[2], acc1[3]);
        *(uint2*)(vtbf + (size_t)(bh * 16 + r) * HW + q0 + 4 * cg) = pk1;
        uint2 pk2; pk2.x = cvtpk(acc2[0], acc2[1]); pk2.y = cvtpk(acc2[2], acc2[3]);
        *(uint2*)(x2t + (size_t)(bh * 16 + r) * HW + q0 + 4 * cg) = pk2;
    } else {
        #pragma unroll
        for (int ri = 0; ri < 4; ++ri) {
            const int q = q0 + 4 * cg + ri;
            qbf[((size_t)bh * HW + q) * 16 + r] = f2bf(acc1[ri] * QSCL);
            kbf[((size_t)bh * HW + q) * 16 + r] = f2bf(acc2[ri]);
        }
    }
}

// ---------------------------------------------------------------------------
// K2: MFMA attention with INLINE channel map. grid (144, 8) x 512 (8 k-split
// waves). Each block streams full K-range -> secm computed in-block (1 extra
// load + 1 MFMA per iter, redundant per block but removes sacc/atomics/init).
// Epilogue: 8-wave merge, secm softmax (shfl groups + tiny LDS), gate from qbf.
// ---------------------------------------------------------------------------
__global__ __launch_bounds__(512) void k_attn(
    const ushort_t* __restrict__ qbf, const ushort_t* __restrict__ kbf,
    const ushort_t* __restrict__ vtbf, const ushort_t* __restrict__ x2t,
    ushort_t* __restrict__ obf)
{
    __shared__ uint4 pbuf4[8][80];          // per-wave P^T tile: 16 q x 80B
    __shared__ f32x4 cacc[8][64];
    __shared__ float clsum[8][64];
    __shared__ f32x4 csec[8][64];
    __shared__ float smv[256];
    const int qt = blockIdx.x, bh = blockIdx.y;
    const int tid = threadIdx.x;
    const int w = tid >> 6, lane = tid & 63;
    const int q16 = lane & 15, g = lane >> 4;
    const int q0 = qt * 16;

    bf16x8 qfrag = {0, 0, 0, 0, 0, 0, 0, 0};
    if (g < 2) qfrag = *(const bf16x8*)(qbf + ((size_t)bh * HW + q0 + q16) * 16 + g * 8);

    unsigned char* pw = (unsigned char*)&pbuf4[w][0];
    const ushort_t* kbase = kbf + (size_t)bh * HW * 16;
    const ushort_t* vbase = vtbf + (size_t)(bh * 16 + q16) * HW;
    const ushort_t* x2base = x2t + (size_t)(bh * 16 + q16) * HW;
    f32x4 oacc = {0.f, 0.f, 0.f, 0.f};
    f32x4 scacc = {0.f, 0.f, 0.f, 0.f};
    float lsum = 0.f;
    const f32x4 zero4 = {0.f, 0.f, 0.f, 0.f};

    #pragma unroll 3
    for (int wi = 0; wi < 9; ++wi) {
        const int k0 = w * 288 + wi * 32;
        bf16x8 kf0 = *(const bf16x8*)(kbase + (size_t)(k0 + q16) * 16 + (g & 1) * 8);
        bf16x8 kf1 = *(const bf16x8*)(kbase + (size_t)(k0 + 16 + q16) * 16 + (g & 1) * 8);
        bf16x8 vfrag = *(const bf16x8*)(vbase + k0 + 8 * g);
        bf16x8 x2frag = *(const bf16x8*)(x2base + k0 + 8 * g);
        f32x4 s0 = MFMA(kf0, qfrag, zero4);
        f32x4 s1 = MFMA(kf1, qfrag, zero4);
        scacc = MFMA(vfrag, x2frag, scacc);   // secm partial: [i=x1d][j=x2d]
        const float e00 = exp2f(s0[0]), e01 = exp2f(s0[1]), e02 = exp2f(s0[2]), e03 = exp2f(s0[3]);
        const float e10 = exp2f(s1[0]), e11 = exp2f(s1[1]), e12 = exp2f(s1[2]), e13 = exp2f(s1[3]);
        lsum += ((e00 + e01) + (e02 + e03)) + ((e10 + e11) + (e12 + e13));
        *(unsigned*)(pw + q16 * 80 + 8 * g)      = cvtpk(e00, e01);
        *(unsigned*)(pw + q16 * 80 + 8 * g + 4)  = cvtpk(e02, e03);
        *(unsigned*)(pw + q16 * 80 + 32 + 8 * g) = cvtpk(e10, e11);
        *(unsigned*)(pw + q16 * 80 + 36 + 8 * g) = cvtpk(e12, e13);
        bf16x8 pfrag = *(const bf16x8*)(pw + q16 * 80 + 16 * g);
        oacc = MFMA(vfrag, pfrag, oacc);
    }
    cacc[w][lane] = oacc;
    clsum[w][lane] = lsum;
    csec[w][lane] = scacc;
    __syncthreads();
    if (tid < 64) {
        f32x4 tt = cacc[0][lane];
        f32x4 sc = csec[0][lane];
        float L = clsum[0][lane];
        #pragma unroll
        for (int ww = 1; ww < 8; ++ww) {
            f32x4 tw = cacc[ww][lane];
            f32x4 sw = csec[ww][lane];
            tt[0] += tw[0]; tt[1] += tw[1]; tt[2] += tw[2]; tt[3] += tw[3];
            sc[0] += sw[0]; sc[1] += sw[1]; sc[2] += sw[2]; sc[3] += sw[3];
            L += clsum[ww][lane];
        }
        L += __shfl_xor(L, 16);
        L += __shfl_xor(L, 32);
        const float invl = 1.f / L;
        // secm softmax: lane holds raw[i=4g+ri][j=q16]; row-reduce across q16 lanes
        #pragma unroll
        for (int ri = 0; ri < 4; ++ri) {
            float v = sc[ri] * SECM_SCL;
            float mx = v;
            mx = fmaxf(mx, __shfl_xor(mx, 1)); mx = fmaxf(mx, __shfl_xor(mx, 2));
            mx = fmaxf(mx, __shfl_xor(mx, 4)); mx = fmaxf(mx, __shfl_xor(mx, 8));
            const float e = __expf(v - mx);
            float su = e;
            su += __shfl_xor(su, 1); su += __shfl_xor(su, 2);
            su += __shfl_xor(su, 4); su += __shfl_xor(su, 8);
            smv[(4 * g + ri) * 16 + q16] = e / su;
        }
        // gate from qbf (y1*QSCL bf16), rescaled
        const ushort_t* yrow = qbf + ((size_t)bh * HW + q0 + q16) * 16;
        float ya[16];
        #pragma unroll
        for (int i = 0; i < 16; ++i) ya[i] = bf2f(yrow[i]) * INV_QSCL;
        float gate[4] = {0.f, 0.f, 0.f, 0.f};
        #pragma unroll
        for (int i = 0; i < 16; ++i) {
            #pragma unroll
            for (int rr = 0; rr < 4; ++rr) gate[rr] += ya[i] * smv[i * 16 + g * 4 + rr];
        }
        const int b = bh >> 2, h = bh & 3;
        float r0 = tt[0] * invl * gate[0];
        float r1 = tt[1] * invl * gate[1];
        float r2 = tt[2] * invl * gate[2];
        float r3 = tt[3] * invl * gate[3];
        uint2 pk; pk.x = cvtpk(r0, r1); pk.y = cvtpk(r2, r3);
        *(uint2*)(obf + ((size_t)b * HW + q0 + q16) * 64 + h * 16 + g * 4) = pk;
    }
}

// ---------------------------------------------------------------------------
// K3: fused tail with inline weight conversion. grid 288 x 256 (4 waves/tile).
// Phase A: outproj jt=w + residual -> xtile. Phase B: mlp1 jt=4w..4w+3 -> hh.
// Phase C: mlp2 jt=w + residual + transposed store.
// ---------------------------------------------------------------------------
__global__ __launch_bounds__(256) void k_tail(
    const ushort_t* __restrict__ obf, const float* __restrict__ x,
    const float* __restrict__ w_out, const float* __restrict__ b_out,
    const float* __restrict__ g2, const float* __restrict__ bt2,
    const float* __restrict__ w1, const float* __restrict__ mb1,
    const float* __restrict__ w2, const float* __restrict__ mb2,
    float* __restrict__ out)
{
    __shared__ float xtile[16][68];          // post-residual tile [row][ch]
    __shared__ ushort_t hh[16 * 264 + 16];   // hidden [row][ch], 528B stride
    const int t = blockIdx.x;
    const int b = t / 144;
    const int q0 = (t % 144) * 16;
    const int tid = threadIdx.x;
    const int w = tid >> 6, lane = tid & 63;
    const int r = lane & 15, cg = lane >> 4;
    const f32x4 zero4 = {0.f, 0.f, 0.f, 0.f};
    // ---- phase A: out-proj + residual (wave w -> out cols w*16..w*16+15)
    const ushort_t* arow = obf + ((size_t)b * HW + q0 + r) * 64;
    bf16x8 alo = *(const bf16x8*)(arow + 8 * cg);
    bf16x8 ahi = *(const bf16x8*)(arow + 32 + 8 * cg);
    {
        const int oc = w * 16 + r;
        U8 bl, bh_;
        #pragma unroll
        for (int p = 0; p < 4; ++p) {
            bl.u[p]  = cvtpk(w_out[(8 * cg + 2 * p) * 64 + oc],      w_out[(8 * cg + 2 * p + 1) * 64 + oc]);
            bh_.u[p] = cvtpk(w_out[(32 + 8 * cg + 2 * p) * 64 + oc], w_out[(32 + 8 * cg + 2 * p + 1) * 64 + oc]);
        }
        f32x4 acc = zero4;
        acc = MFMA(alo, bl.v, acc);
        acc = MFMA(ahi, bh_.v, acc);
        const float bo = b_out[oc];
        float4 xr = *(const float4*)(x + (size_t)b * CH * HW + (size_t)oc * HW + q0 + 4 * cg);
        xtile[4 * cg + 0][oc] = acc[0] + bo + xr.x;
        xtile[4 * cg + 1][oc] = acc[1] + bo + xr.y;
        xtile[4 * cg + 2][oc] = acc[2] + bo + xr.z;
        xtile[4 * cg + 3][oc] = acc[3] + bo + xr.w;
    }
    __syncthreads();
    // ---- LN2 stats for row r
    float s = 0.f, sq = 0.f;
    #pragma unroll
    for (int j = 0; j < 16; ++j) {
        const float v = xtile[r][cg * 16 + j];
        s += v; sq += v * v;
    }
    s  += __shfl_xor(s, 16);  s  += __shfl_xor(s, 32);
    sq += __shfl_xor(sq, 16); sq += __shfl_xor(sq, 32);
    const float m  = s * (1.f / 64.f);
    const float rs = rsqrtf(sq * (1.f / 64.f) - m * m + 1e-5f);
    float ga[16], be[16];
    {
        const float4* gp = (const float4*)g2;
        const float4* bp = (const float4*)bt2;
        *(float4*)&ga[0]  = gp[2 * cg];     *(float4*)&ga[4]  = gp[2 * cg + 1];
        *(float4*)&ga[8]  = gp[8 + 2 * cg]; *(float4*)&ga[12] = gp[9 + 2 * cg];
        *(float4*)&be[0]  = bp[2 * cg];     *(float4*)&be[4]  = bp[2 * cg + 1];
        *(float4*)&be[8]  = bp[8 + 2 * cg]; *(float4*)&be[12] = bp[9 + 2 * cg];
    }
    float nlo[8], nhi[8];
    #pragma unroll
    for (int ki = 0; ki < 8; ++ki) {
        nlo[ki] = (xtile[r][8 * cg + ki]      - m) * rs * ga[ki]     + be[ki];
        nhi[ki] = (xtile[r][32 + 8 * cg + ki] - m) * rs * ga[8 + ki] + be[8 + ki];
    }
    U8 axlo, axhi;
    #pragma unroll
    for (int p = 0; p < 4; ++p) {
        axlo.u[p] = cvtpk(nlo[2 * p], nlo[2 * p + 1]);
        axhi.u[p] = cvtpk(nhi[2 * p], nhi[2 * p + 1]);
    }
    // ---- phase B: mlp1 + LeakyReLU (wave w -> hidden cols 4w*16..)
    #pragma unroll
    for (int jj = 0; jj < 4; ++jj) {
        const int jt = 4 * w + jj;
        const int hc = jt * 16 + r;
        U8 bl, bh_;
        #pragma unroll
        for (int p = 0; p < 4; ++p) {
            bl.u[p]  = cvtpk(w1[(8 * cg + 2 * p) * 256 + hc],      w1[(8 * cg + 2 * p + 1) * 256 + hc]);
            bh_.u[p] = cvtpk(w1[(32 + 8 * cg + 2 * p) * 256 + hc], w1[(32 + 8 * cg + 2 * p + 1) * 256 + hc]);
        }
        f32x4 acc = zero4;
        acc = MFMA(axlo.v, bl.v, acc);
        acc = MFMA(axhi.v, bh_.v, acc);
        const float bias = mb1[hc];
        #pragma unroll
        for (int ri = 0; ri < 4; ++ri) {
            float vv = acc[ri] + bias;
            vv = fmaxf(vv, 0.01f * vv);
            hh[(4 * cg + ri) * 264 + hc] = f2bf(vv);
        }
    }
    __syncthreads();
    // ---- phase C: mlp2 + residual + transposed store (wave w -> out cols w*16..)
    const int oc = w * 16 + r;
    f32x4 acc = zero4;
    #pragma unroll
    for (int kw = 0; kw < 8; ++kw) {
        bf16x8 ha = *(const bf16x8*)&hh[r * 264 + kw * 32 + 8 * cg];
        U8 bf_;
        #pragma unroll
        for (int p = 0; p < 4; ++p)
            bf_.u[p] = cvtpk(w2[(kw * 32 + 8 * cg + 2 * p) * 64 + oc],
                             w2[(kw * 32 + 8 * cg + 2 * p + 1) * 64 + oc]);
        acc = MFMA(ha, bf_.v, acc);
    }
    const float bias = mb2[oc];
    float4 res;
    res.x = acc[0] + bias + xtile[4 * cg + 0][oc];
    res.y = acc[1] + bias + xtile[4 * cg + 1][oc];
    res.z = acc[2] + bias + xtile[4 * cg + 2][oc];
    res.w = acc[3] + bias + xtile[4 * cg + 3][oc];
    *(float4*)(out + (size_t)b * CH * HW + (size_t)oc * HW + q0 + 4 * cg) = res;
}

extern "C" void kernel_launch(void* const* d_in, const int* in_sizes, int n_in,
                              void* d_out, int out_size, void* d_ws, size_t ws_size,
                              hipStream_t stream)
{
    (void)in_sizes; (void)n_in; (void)out_size; (void)ws_size;
    const float* x     = (const float*)d_in[0];
    const float* y     = (const float*)d_in[1];
    const float* ln1_g = (const float*)d_in[2];
    const float* ln1_b = (const float*)d_in[3];
    const float* w_sa1 = (const float*)d_in[4];
    const float* w_sa2 = (const float*)d_in[5];
    const float* w_se1 = (const float*)d_in[6];
    const float* w_se2 = (const float*)d_in[7];
    const float* w_out = (const float*)d_in[8];
    const float* b_out = (const float*)d_in[9];
    const float* ln2_g = (const float*)d_in[10];
    const float* ln2_b = (const float*)d_in[11];
    const float* w1    = (const float*)d_in[12];
    const float* b1    = (const float*)d_in[13];
    const float* w2    = (const float*)d_in[14];
    const float* b2    = (const float*)d_in[15];
    float* out = (float*)d_out;

    const size_t NP = 8ull * HW * 16;              // 294912
    ushort_t* u = (ushort_t*)d_ws;
    ushort_t* qbf   = u;  u += NP;
    ushort_t* kbf   = u;  u += NP;
    ushort_t* vtbf  = u;  u += NP;
    ushort_t* x2t   = u;  u += NP;
    ushort_t* obf   = u;  u += NP;
    // total ~2.95 MB of d_ws

    k_ln_proj<<<dim3(576, 4), 64, 0, stream>>>(x, y, ln1_g, ln1_b,
                                               w_sa1, w_sa2, w_se1, w_se2,
                                               qbf, kbf, vtbf, x2t);
    k_attn<<<dim3(144, 8), 512, 0, stream>>>(qbf, kbf, vtbf, x2t, obf);
    k_tail<<<288, 256, 0, stream>>>(obf, x, w_out, b_out, ln2_g, ln2_b,
                                    w1, b1, w2, b2, out);
}